// Round 1
// baseline (4586.293 us; speedup 1.0000x reference)
//
#include <hip/hip_runtime.h>
#include <stdint.h>

#define N_PTS 100000
#define NPAD  100032   // 64*1563, padded row count for MFMA row tiles

typedef unsigned short u16;
using bf16x8 = __attribute__((ext_vector_type(8))) short;
using f32x4  = __attribute__((ext_vector_type(4))) float;

__device__ __forceinline__ u16 f2bf(float f) {
    uint32_t u = __float_as_uint(f);
    u += 0x7FFFu + ((u >> 16) & 1u);   // round-to-nearest-even
    return (u16)(u >> 16);
}
__device__ __forceinline__ float bf2f(u16 h) {
    return __uint_as_float(((uint32_t)h) << 16);
}

// ---------------- weight transpose to bf16 B-layout: dst[l][co][ci] = src[l][ci][co]
__global__ __launch_bounds__(256) void k_transpose_bf16(
    const float* __restrict__ src, u16* __restrict__ dst, int Lc, int R, int Cc) {
    int t = blockIdx.x * 256 + threadIdx.x;
    int total = Lc * R * Cc;
    if (t >= total) return;
    int l = t / (R * Cc);
    int rem = t - l * (R * Cc);
    int co = rem / R;
    int ci = rem - co * R;
    dst[t] = f2bf(src[((size_t)l * R + ci) * Cc + co]);
}

// ---------------- PPF features: f5[i][k] = {ang(ni,d), ang(nj,d), ang(ni,nj), dist, dist/r}
__device__ __forceinline__ float angf(float ax, float ay, float az,
                                      float bx, float by, float bz) {
    float cx = ay * bz - az * by;
    float cy = az * bx - ax * bz;
    float cz = ax * by - ay * bx;
    float cr = sqrtf(cx * cx + cy * cy + cz * cz);
    float dt = ax * bx + ay * by + az * bz;
    return atan2f(cr, dt);
}

__global__ __launch_bounds__(256) void k_ppf(
    const float* __restrict__ p, const float* __restrict__ nrm,
    const int* __restrict__ idx, const float* __restrict__ r,
    float* __restrict__ f5) {
    int t = blockIdx.x * 256 + threadIdx.x;
    if (t >= N_PTS * 16) return;
    int i = t >> 4, k = t & 15;
    int j = idx[(size_t)i * 32 + k];
    float pix = p[(size_t)i*3], piy = p[(size_t)i*3+1], piz = p[(size_t)i*3+2];
    float pjx = p[(size_t)j*3], pjy = p[(size_t)j*3+1], pjz = p[(size_t)j*3+2];
    float dx = pjx - pix, dy = pjy - piy, dz = pjz - piz;
    float dist = sqrtf(dx*dx + dy*dy + dz*dz);
    float nix = nrm[(size_t)i*3], niy = nrm[(size_t)i*3+1], niz = nrm[(size_t)i*3+2];
    float njx = nrm[(size_t)j*3], njy = nrm[(size_t)j*3+1], njz = nrm[(size_t)j*3+2];
    float a1 = angf(nix, niy, niz, dx, dy, dz);
    float a2 = angf(njx, njy, njz, dx, dy, dz);
    float a3 = angf(nix, niy, niz, njx, njy, njz);
    float rinv = 1.0f / r[0];
    float* o = f5 + (size_t)t * 5;
    o[0] = a1; o[1] = a2; o[2] = a3; o[3] = dist; o[4] = dist * rinv;
}

// ---------------- neighbor stage (per layer): emb MLP + gather + conv + maxpool -> pooled
// grid = N/4 blocks, 256 threads (4 waves); wave w handles point i0+w (16 neighbor rows).
__global__ __launch_bounds__(256) void k_neighbor(
    const float* __restrict__ xcur,   // gather source [>=N][256] fp32
    const float* __restrict__ f5,     // [N][16][5]
    const int*   __restrict__ idx,    // [N][32], first 16 used
    const float* __restrict__ w1,     // emb_w1 layer [5][256]
    const float* __restrict__ g1,     // emb_g1 [256]
    const float* __restrict__ b1,     // emb_b1 [256]
    const u16*   __restrict__ ew2t,   // emb_w2 transposed bf16 [256 cout][256 cin]
    const float* __restrict__ convw,  // conv_w layer [64][64] fp32
    float*       __restrict__ pooled) // out [NPAD][256] fp32 (rows < N written)
{
    __shared__ u16 w1t[256 * 40];     // B-layout [c][k], k<5 real, 5..31 zero
    __shared__ u16 convs[64 * 72];    // [d][c] bf16 (B[k=c][n=d] readable)
    __shared__ u16 hbuf[4][16 * 264]; // per-wave h rows (post LN+leaky) bf16
    __shared__ u16 Bs[16 * 264];      // staged ew2t tile: 16 couts x 256 k
    __shared__ u16 gbuf[4][16 * 72];  // per-wave g[:, :64] bf16
    __shared__ int idxs[4][16];

    const int tid = threadIdx.x;
    const int i0 = blockIdx.x * 4;

    {   // stage w1t: one column per thread
        int c = tid;
        #pragma unroll
        for (int k = 0; k < 32; ++k)
            w1t[c * 40 + k] = (k < 5) ? f2bf(w1[k * 256 + c]) : (u16)0;
    }
    for (int t = tid; t < 4096; t += 256)
        convs[(t >> 6) * 72 + (t & 63)] = f2bf(convw[t]);
    if (tid < 64)
        idxs[tid >> 4][tid & 15] = idx[(size_t)(i0 + (tid >> 4)) * 32 + (tid & 15)];
    __syncthreads();

    const int w = tid >> 6, lane = tid & 63;
    const int rr = lane & 15, q = lane >> 4;
    const int i = i0 + w;

    // ---- emb: h = f5pad(16x32) @ w1pad(32x256), then LN + leaky -> hbuf bf16 ----
    bf16x8 a1;
    #pragma unroll
    for (int e = 0; e < 8; ++e) a1[e] = 0;
    if (q == 0) {
        const float* fp = f5 + ((size_t)i * 16 + rr) * 5;
        a1[0] = (short)f2bf(fp[0]); a1[1] = (short)f2bf(fp[1]);
        a1[2] = (short)f2bf(fp[2]); a1[3] = (short)f2bf(fp[3]);
        a1[4] = (short)f2bf(fp[4]);
    }
    f32x4 hacc[16];
    #pragma unroll
    for (int nt = 0; nt < 16; ++nt) {
        f32x4 z = {0.f, 0.f, 0.f, 0.f};
        bf16x8 b = *(const bf16x8*)&w1t[(nt * 16 + rr) * 40 + q * 8];
        hacc[nt] = __builtin_amdgcn_mfma_f32_16x16x32_bf16(a1, b, z, 0, 0, 0);
    }
    float meanj[4], rstdj[4];
    #pragma unroll
    for (int j = 0; j < 4; ++j) {
        float s = 0.f, z2 = 0.f;
        #pragma unroll
        for (int nt = 0; nt < 16; ++nt) { float v = hacc[nt][j]; s += v; z2 += v * v; }
        s  += __shfl_xor(s, 1);  s  += __shfl_xor(s, 2);
        s  += __shfl_xor(s, 4);  s  += __shfl_xor(s, 8);
        z2 += __shfl_xor(z2, 1); z2 += __shfl_xor(z2, 2);
        z2 += __shfl_xor(z2, 4); z2 += __shfl_xor(z2, 8);
        float mean = s * (1.f / 256.f);
        float var = fmaxf(z2 * (1.f / 256.f) - mean * mean, 0.f);
        meanj[j] = mean;
        rstdj[j] = 1.0f / sqrtf(var + 1e-5f);
    }
    u16* hb = &hbuf[w][0];
    #pragma unroll
    for (int nt = 0; nt < 16; ++nt) {
        const int c = nt * 16 + rr;
        const float gg = g1[c], bb = b1[c];
        #pragma unroll
        for (int j = 0; j < 4; ++j) {
            float v = (hacc[nt][j] - meanj[j]) * rstdj[j] * gg + bb;
            v = v > 0.f ? v : 0.1f * v;           // leaky_relu
            hb[(4 * q + j) * 264 + c] = f2bf(v);
        }
    }
    // A-fragments for the 256x256 GEMM, held in registers
    bf16x8 afr[8];
    #pragma unroll
    for (int kb = 0; kb < 8; ++kb)
        afr[kb] = *(const bf16x8*)&hb[rr * 264 + kb * 32 + q * 8];

    const float* xr0 = xcur + (size_t)idxs[w][4 * q + 0] * 256;
    const float* xr1 = xcur + (size_t)idxs[w][4 * q + 1] * 256;
    const float* xr2 = xcur + (size_t)idxs[w][4 * q + 2] * 256;
    const float* xr3 = xcur + (size_t)idxs[w][4 * q + 3] * 256;
    float* poolrow = pooled + (size_t)i * 256;

    #pragma unroll 1
    for (int nt = 0; nt < 16; ++nt) {
        __syncthreads();
        // stage B tile (16 output cols x 256 k), shared by all 4 waves
        #pragma unroll
        for (int c2 = tid; c2 < 512; c2 += 256) {
            int rowb = c2 >> 5, ko = (c2 & 31) * 8;
            *(uint4*)&Bs[rowb * 264 + ko] =
                *(const uint4*)&ew2t[(size_t)(nt * 16 + rowb) * 256 + ko];
        }
        __syncthreads();
        f32x4 acc = {0.f, 0.f, 0.f, 0.f};
        #pragma unroll
        for (int kb = 0; kb < 8; ++kb) {
            bf16x8 b = *(const bf16x8*)&Bs[rr * 264 + kb * 32 + q * 8];
            acc = __builtin_amdgcn_mfma_f32_16x16x32_bf16(afr[kb], b, acc, 0, 0, 0);
        }
        const int c = nt * 16 + rr;   // output channel
        float gv0 = xr0[c] + acc[0];
        float gv1 = xr1[c] + acc[1];
        float gv2 = xr2[c] + acc[2];
        float gv3 = xr3[c] + acc[3];
        if (nt < 4) {
            // channels 0..63 feed the conv; stash g in LDS (bf16)
            gbuf[w][(4 * q + 0) * 72 + c] = f2bf(gv0);
            gbuf[w][(4 * q + 1) * 72 + c] = f2bf(gv1);
            gbuf[w][(4 * q + 2) * 72 + c] = f2bf(gv2);
            gbuf[w][(4 * q + 3) * 72 + c] = f2bf(gv3);
            if (nt == 3) {
                // conv: g1 = g[:, :64] @ conv_w^T, then maxpool over the 16 rows
                bf16x8 a20 = *(const bf16x8*)&gbuf[w][rr * 72 + q * 8];
                bf16x8 a21 = *(const bf16x8*)&gbuf[w][rr * 72 + 32 + q * 8];
                #pragma unroll
                for (int cn = 0; cn < 4; ++cn) {
                    f32x4 acc2 = {0.f, 0.f, 0.f, 0.f};
                    bf16x8 b20 = *(const bf16x8*)&convs[(cn * 16 + rr) * 72 + q * 8];
                    bf16x8 b21 = *(const bf16x8*)&convs[(cn * 16 + rr) * 72 + 32 + q * 8];
                    acc2 = __builtin_amdgcn_mfma_f32_16x16x32_bf16(a20, b20, acc2, 0, 0, 0);
                    acc2 = __builtin_amdgcn_mfma_f32_16x16x32_bf16(a21, b21, acc2, 0, 0, 0);
                    float m = fmaxf(fmaxf(acc2[0], acc2[1]), fmaxf(acc2[2], acc2[3]));
                    m = fmaxf(m, __shfl_xor(m, 16));
                    m = fmaxf(m, __shfl_xor(m, 32));
                    if (lane < 16) poolrow[cn * 16 + lane] = m;
                }
            }
        } else {
            float m = fmaxf(fmaxf(gv0, gv1), fmaxf(gv2, gv3));
            m = fmaxf(m, __shfl_xor(m, 16));
            m = fmaxf(m, __shfl_xor(m, 32));
            if (lane < 16) poolrow[c] = m;
        }
    }
}

// ---------------- pointwise stage (per layer), fully fused:
// x_next = relu(LN2(leaky(LN1(pooled @ W1)) @ W2) + xres)
// grid = NPAD/64 blocks, 256 threads; wave w owns rows [R0, R0+16).
// NOTE: xnext may alias pool (wave reads its pooled rows into regs first).
__global__ __launch_bounds__(256) void k_pointwise(
    const float* pool,                 // [NPAD][256] fp32 (own rows only)
    const float* __restrict__ xres,    // residual source
    float*       xnext,                // [NPAD][256] fp32
    const u16*   __restrict__ b1t,     // pw_w1^T bf16 [1024][256]
    const float* __restrict__ g1, const float* __restrict__ b1,  // [1024]
    const u16*   __restrict__ b2t,     // pw_w2^T bf16 [256][1024]
    const float* __restrict__ g2, const float* __restrict__ b2,  // [256]
    int guardRes)                      // 1 if xres has only N rows
{
    __shared__ u16 hm[4][16 * 1032];   // per-wave h_mid 16 x 1024 (+8 pad) bf16
    __shared__ float stats[4][16][2];

    const int tid = threadIdx.x, w = tid >> 6, lane = tid & 63;
    const int rr = lane & 15, q = lane >> 4;
    const size_t R0 = (size_t)blockIdx.x * 64 + (size_t)w * 16;

    // GEMM1 A fragments (pooled rows) -> registers, bf16
    const float* arow = pool + (R0 + rr) * 256;
    bf16x8 afr[8];
    #pragma unroll
    for (int kb = 0; kb < 8; ++kb) {
        const float* s0 = arow + kb * 32 + q * 8;
        bf16x8 a;
        #pragma unroll
        for (int e = 0; e < 8; ++e) a[e] = (short)f2bf(s0[e]);
        afr[kb] = a;
    }

    u16* hmw = &hm[w][0];
    float sums[4] = {0.f, 0.f, 0.f, 0.f}, ssqs[4] = {0.f, 0.f, 0.f, 0.f};
    #pragma unroll 1
    for (int cp = 0; cp < 4; ++cp) {
        #pragma unroll 2
        for (int nt = 0; nt < 16; ++nt) {
            const int co = cp * 256 + nt * 16 + rr;   // output col 0..1023
            const u16* bp = b1t + (size_t)co * 256 + q * 8;
            f32x4 acc = {0.f, 0.f, 0.f, 0.f};
            #pragma unroll
            for (int kb = 0; kb < 8; ++kb) {
                bf16x8 b = *(const bf16x8*)(bp + kb * 32);
                acc = __builtin_amdgcn_mfma_f32_16x16x32_bf16(afr[kb], b, acc, 0, 0, 0);
            }
            #pragma unroll
            for (int j = 0; j < 4; ++j) {
                hmw[(4 * q + j) * 1032 + co] = f2bf(acc[j]);
                sums[j] += acc[j];
                ssqs[j] += acc[j] * acc[j];
            }
        }
    }
    // LN1 stats per row
    #pragma unroll
    for (int j = 0; j < 4; ++j) {
        float s = sums[j], z = ssqs[j];
        s += __shfl_xor(s, 1); s += __shfl_xor(s, 2);
        s += __shfl_xor(s, 4); s += __shfl_xor(s, 8);
        z += __shfl_xor(z, 1); z += __shfl_xor(z, 2);
        z += __shfl_xor(z, 4); z += __shfl_xor(z, 8);
        if (rr == 0) {
            float mean = s * (1.f / 1024.f);
            float var = fmaxf(z * (1.f / 1024.f) - mean * mean, 0.f);
            stats[w][4 * q + j][0] = mean;
            stats[w][4 * q + j][1] = 1.0f / sqrtf(var + 1e-5f);
        }
    }
    // normalize + leaky in LDS: lane covers cols [lane*16, lane*16+16)
    {
        float g1v[16], b1v[16];
        #pragma unroll
        for (int e = 0; e < 16; ++e) { g1v[e] = g1[lane * 16 + e]; b1v[e] = b1[lane * 16 + e]; }
        #pragma unroll 1
        for (int row = 0; row < 16; ++row) {
            float mean = stats[w][row][0], rstd = stats[w][row][1];
            u16* hp = &hmw[row * 1032 + lane * 16];
            #pragma unroll
            for (int e2 = 0; e2 < 8; ++e2) {
                uint32_t pk = *(uint32_t*)(hp + e2 * 2);
                float v0 = bf2f((u16)(pk & 0xffffu));
                float v1 = bf2f((u16)(pk >> 16));
                v0 = (v0 - mean) * rstd * g1v[e2 * 2] + b1v[e2 * 2];
                v1 = (v1 - mean) * rstd * g1v[e2 * 2 + 1] + b1v[e2 * 2 + 1];
                v0 = v0 > 0.f ? v0 : 0.1f * v0;
                v1 = v1 > 0.f ? v1 : 0.1f * v1;
                *(uint32_t*)(hp + e2 * 2) = (uint32_t)f2bf(v0) | ((uint32_t)f2bf(v1) << 16);
            }
        }
    }
    // GEMM2: 16 rows x 256 cols, K=1024. Full unroll for static acc2 indexing.
    f32x4 acc2[16];
    #pragma unroll
    for (int nt = 0; nt < 16; ++nt) acc2[nt] = (f32x4){0.f, 0.f, 0.f, 0.f};
    #pragma unroll
    for (int nt = 0; nt < 16; ++nt) {
        const u16* bp = b2t + (size_t)(nt * 16 + rr) * 1024 + q * 8;
        const u16* ap = hmw + rr * 1032 + q * 8;
        f32x4 acc = acc2[nt];
        #pragma unroll
        for (int kb = 0; kb < 32; ++kb) {
            bf16x8 a = *(const bf16x8*)(ap + kb * 32);
            bf16x8 b = *(const bf16x8*)(bp + kb * 32);
            acc = __builtin_amdgcn_mfma_f32_16x16x32_bf16(a, b, acc, 0, 0, 0);
        }
        acc2[nt] = acc;
    }
    // LN2 stats
    float mean2[4], rstd2[4];
    #pragma unroll
    for (int j = 0; j < 4; ++j) {
        float s = 0.f, z = 0.f;
        #pragma unroll
        for (int nt = 0; nt < 16; ++nt) { float v = acc2[nt][j]; s += v; z += v * v; }
        s += __shfl_xor(s, 1); s += __shfl_xor(s, 2);
        s += __shfl_xor(s, 4); s += __shfl_xor(s, 8);
        z += __shfl_xor(z, 1); z += __shfl_xor(z, 2);
        z += __shfl_xor(z, 4); z += __shfl_xor(z, 8);
        float mean = s * (1.f / 256.f);
        float var = fmaxf(z * (1.f / 256.f) - mean * mean, 0.f);
        mean2[j] = mean;
        rstd2[j] = 1.0f / sqrtf(var + 1e-5f);
    }
    // epilogue: LN2 affine + residual + relu
    #pragma unroll
    for (int nt = 0; nt < 16; ++nt) {
        const int c = nt * 16 + rr;
        const float gg = g2[c], bb = b2[c];
        #pragma unroll
        for (int j = 0; j < 4; ++j) {
            const size_t row = R0 + 4 * q + j;
            float v = (acc2[nt][j] - mean2[j]) * rstd2[j] * gg + bb;
            float xv = 0.f;
            if (!guardRes || row < (size_t)N_PTS) xv = xres[row * 256 + c];
            float o = v + xv;
            xnext[row * 256 + c] = o > 0.f ? o : 0.f;
        }
    }
}

// ---------------- final projection: out = x @ proj_w + proj_b
__global__ __launch_bounds__(256) void k_proj(
    const float* __restrict__ xin,   // [NPAD][256]
    const u16*   __restrict__ pjt,   // proj_w^T bf16 [256][256]
    const float* __restrict__ pb,    // [256]
    float*       __restrict__ out)   // [N][256]
{
    const int tid = threadIdx.x, w = tid >> 6, lane = tid & 63;
    const int rr = lane & 15, q = lane >> 4;
    const size_t R0 = (size_t)blockIdx.x * 64 + (size_t)w * 16;
    const float* arow = xin + (R0 + rr) * 256;
    bf16x8 afr[8];
    #pragma unroll
    for (int kb = 0; kb < 8; ++kb) {
        const float* s0 = arow + kb * 32 + q * 8;
        bf16x8 a;
        #pragma unroll
        for (int e = 0; e < 8; ++e) a[e] = (short)f2bf(s0[e]);
        afr[kb] = a;
    }
    #pragma unroll 2
    for (int nt = 0; nt < 16; ++nt) {
        const u16* bp = pjt + (size_t)(nt * 16 + rr) * 256 + q * 8;
        f32x4 acc = {0.f, 0.f, 0.f, 0.f};
        #pragma unroll
        for (int kb = 0; kb < 8; ++kb) {
            bf16x8 b = *(const bf16x8*)(bp + kb * 32);
            acc = __builtin_amdgcn_mfma_f32_16x16x32_bf16(afr[kb], b, acc, 0, 0, 0);
        }
        const int c = nt * 16 + rr;
        const float bias = pb[c];
        #pragma unroll
        for (int j = 0; j < 4; ++j) {
            const size_t row = R0 + 4 * q + j;
            if (row < (size_t)N_PTS) out[row * 256 + c] = acc[j] + bias;
        }
    }
}

extern "C" void kernel_launch(void* const* d_in, const int* in_sizes, int n_in,
                              void* d_out, int out_size, void* d_ws, size_t ws_size,
                              hipStream_t stream) {
    const float* p      = (const float*)d_in[0];
    const float* x      = (const float*)d_in[1];
    const float* nn     = (const float*)d_in[2];
    const int*   idx    = (const int*)d_in[3];
    const float* r      = (const float*)d_in[4];
    const float* emb_w1 = (const float*)d_in[5];
    const float* emb_g1 = (const float*)d_in[6];
    const float* emb_b1 = (const float*)d_in[7];
    const float* emb_w2 = (const float*)d_in[8];
    const float* conv_w = (const float*)d_in[9];
    const float* pw_w1  = (const float*)d_in[10];
    const float* pw_g1  = (const float*)d_in[11];
    const float* pw_b1  = (const float*)d_in[12];
    const float* pw_w2  = (const float*)d_in[13];
    const float* pw_g2  = (const float*)d_in[14];
    const float* pw_b2  = (const float*)d_in[15];
    const float* proj_w = (const float*)d_in[16];
    const float* proj_b = (const float*)d_in[17];
    float* out = (float*)d_out;

    char* ws = (char*)d_ws;
    const size_t SZX = (size_t)NPAD * 256 * 4;       // 102,432,768 B
    float* P  = (float*)ws;                          // pooled/x buffer A
    float* X  = (float*)(ws + SZX);                  // pooled/x buffer B
    float* f5 = (float*)(ws + 2 * SZX);              // [N][16][5] fp32, 32 MB
    char*  wb = ws + 2 * SZX + (size_t)N_PTS * 16 * 5 * 4;
    u16* ew2t = (u16*)wb;                            // 2*256*256
    u16* b1t  = ew2t + 2 * 256 * 256;                // 2*1024*256
    u16* b2t  = b1t + 2 * 1024 * 256;                // 2*256*1024
    u16* pjt  = b2t + 2 * 256 * 1024;                // 256*256
    // total ws use ~= 239.4 MB

    // weight prep (bf16 transposed B-layouts)
    k_transpose_bf16<<<(2 * 256 * 256 + 255) / 256, 256, 0, stream>>>(emb_w2, ew2t, 2, 256, 256);
    k_transpose_bf16<<<(2 * 1024 * 256 + 255) / 256, 256, 0, stream>>>(pw_w1, b1t, 2, 256, 1024);
    k_transpose_bf16<<<(2 * 256 * 1024 + 255) / 256, 256, 0, stream>>>(pw_w2, b2t, 2, 1024, 256);
    k_transpose_bf16<<<(256 * 256 + 255) / 256, 256, 0, stream>>>(proj_w, pjt, 1, 256, 256);

    // PPF features (shared by both layers)
    k_ppf<<<(N_PTS * 16 + 255) / 256, 256, 0, stream>>>(p, nn, idx, r, f5);

    // layer 0: x_in -> P
    k_neighbor<<<N_PTS / 4, 256, 0, stream>>>(x, f5, idx, emb_w1, emb_g1, emb_b1,
                                              ew2t, conv_w, P);
    k_pointwise<<<NPAD / 64, 256, 0, stream>>>(P, x, P, b1t, pw_g1, pw_b1,
                                               b2t, pw_g2, pw_b2, 1);
    // layer 1: P -> X
    k_neighbor<<<N_PTS / 4, 256, 0, stream>>>(P, f5, idx, emb_w1 + 5 * 256,
                                              emb_g1 + 256, emb_b1 + 256,
                                              ew2t + 256 * 256, conv_w + 64 * 64, X);
    k_pointwise<<<NPAD / 64, 256, 0, stream>>>(X, P, X, b1t + 1024 * 256,
                                               pw_g1 + 1024, pw_b1 + 1024,
                                               b2t + 256 * 1024, pw_g2 + 256, pw_b2 + 256, 0);
    // projection
    k_proj<<<NPAD / 64, 256, 0, stream>>>(X, pjt, proj_b, out);
}

// Round 2
// 3790.142 us; speedup vs baseline: 1.2101x; 1.2101x over previous
//
#include <hip/hip_runtime.h>
#include <stdint.h>

#define N_PTS 100000
#define NPAD  100032   // 64*1563

typedef unsigned short u16;
using bf16x8 = __attribute__((ext_vector_type(8))) short;
using f32x4  = __attribute__((ext_vector_type(4))) float;

__device__ __forceinline__ u16 f2bf(float f) {
    uint32_t u = __float_as_uint(f);
    u += 0x7FFFu + ((u >> 16) & 1u);   // RNE
    return (u16)(u >> 16);
}
__device__ __forceinline__ float bf2f(u16 h) {
    return __uint_as_float(((uint32_t)h) << 16);
}

// ---------- generic padded transpose to bf16: dst[l][co][stride] = src[l][ci][co] (ci<R else 0)
__global__ __launch_bounds__(256) void k_transpose_pad(
    const float* __restrict__ src, u16* __restrict__ dst,
    int Lc, int R, int Cc, int stride) {
    int t = blockIdx.x * 256 + threadIdx.x;
    int total = Lc * Cc * stride;
    if (t >= total) return;
    int l = t / (Cc * stride);
    int rem = t - l * (Cc * stride);
    int co = rem / stride;
    int ci = rem - co * stride;
    dst[t] = (ci < R) ? f2bf(src[((size_t)l * R + ci) * Cc + co]) : (u16)0;
}

__global__ __launch_bounds__(256) void k_cast_bf16(
    const float* __restrict__ src, u16* __restrict__ dst, int total) {
    int t = blockIdx.x * 256 + threadIdx.x;
    if (t < total) dst[t] = f2bf(src[t]);
}

// ---------- PPF features
__device__ __forceinline__ float angf(float ax, float ay, float az,
                                      float bx, float by, float bz) {
    float cx = ay * bz - az * by;
    float cy = az * bx - ax * bz;
    float cz = ax * by - ay * bx;
    float cr = sqrtf(cx * cx + cy * cy + cz * cz);
    float dt = ax * bx + ay * by + az * bz;
    return atan2f(cr, dt);
}

__global__ __launch_bounds__(256) void k_ppf(
    const float* __restrict__ p, const float* __restrict__ nrm,
    const int* __restrict__ idx, const float* __restrict__ r,
    float* __restrict__ f5) {
    int t = blockIdx.x * 256 + threadIdx.x;
    if (t >= N_PTS * 16) return;
    int i = t >> 4, k = t & 15;
    int j = idx[(size_t)i * 32 + k];
    float pix = p[(size_t)i*3], piy = p[(size_t)i*3+1], piz = p[(size_t)i*3+2];
    float pjx = p[(size_t)j*3], pjy = p[(size_t)j*3+1], pjz = p[(size_t)j*3+2];
    float dx = pjx - pix, dy = pjy - piy, dz = pjz - piz;
    float dist = sqrtf(dx*dx + dy*dy + dz*dz);
    float nix = nrm[(size_t)i*3], niy = nrm[(size_t)i*3+1], niz = nrm[(size_t)i*3+2];
    float njx = nrm[(size_t)j*3], njy = nrm[(size_t)j*3+1], njz = nrm[(size_t)j*3+2];
    float a1 = angf(nix, niy, niz, dx, dy, dz);
    float a2 = angf(njx, njy, njz, dx, dy, dz);
    float a3 = angf(nix, niy, niz, njx, njy, njz);
    float rinv = 1.0f / r[0];
    float* o = f5 + (size_t)t * 5;
    o[0] = a1; o[1] = a2; o[2] = a3; o[3] = dist; o[4] = dist * rinv;
}

// ---------- neighbor stage v2: 16 points/block, 512 threads (8 waves), wave owns 2 points.
__global__ __launch_bounds__(512, 2) void k_neighbor(
    const float* __restrict__ xcur,   // gather source [NPAD][256] fp32 (rows <N valid)
    const float* __restrict__ f5,     // [N][16][5]
    const int*   __restrict__ idx,    // [N][32]
    const u16*   __restrict__ w1pad,  // emb_w1^T padded bf16 [256][32] (k<5 real)
    const float* __restrict__ g1, const float* __restrict__ b1,   // [256]
    const u16*   __restrict__ ew2tp,  // emb_w2^T padded bf16 [256][264]
    const u16*   __restrict__ convbf, // conv_w bf16 [64][64]
    float*       __restrict__ pooled) // [NPAD][256] fp32, rows <N written
{
    __shared__ u16 Bs[128 * 264];     // 67,584 B : staged ew2t half (128 couts x 256k +pad)
    __shared__ u16 scratch[8][4224];  // 67,584 B : per-wave h-stage (16x264) / conv gbuf (32x72)
    __shared__ int idxs[16][16];      // 1,024 B

    const int tid = threadIdx.x, w = tid >> 6, lane = tid & 63;
    const int rr = lane & 15, q = lane >> 4;
    const int i0 = blockIdx.x * 16;

    // stage B half 0 (linear copy; overlapped with emb compute below)
    for (int o = tid * 16; o < 67584; o += 8192)
        *(uint4*)((char*)Bs + o) = *(const uint4*)((const char*)ew2tp + o);
    if (tid < 256)
        idxs[tid >> 4][tid & 15] = idx[(size_t)(i0 + (tid >> 4)) * 32 + (tid & 15)];

    u16* sw = &scratch[w][0];
    bf16x8 afr[2][8];

    // ---- emb MLP per row-tile (point): h = leaky(LN(f5pad @ w1)), A-frags to regs ----
    #pragma unroll
    for (int rt = 0; rt < 2; ++rt) {
        const int pt = i0 + 2 * w + rt;
        bf16x8 a1;
        #pragma unroll
        for (int e = 0; e < 8; ++e) a1[e] = 0;
        if (q == 0) {
            const float* fp = f5 + ((size_t)pt * 16 + rr) * 5;
            a1[0] = (short)f2bf(fp[0]); a1[1] = (short)f2bf(fp[1]);
            a1[2] = (short)f2bf(fp[2]); a1[3] = (short)f2bf(fp[3]);
            a1[4] = (short)f2bf(fp[4]);
        }
        f32x4 hacc[16];
        #pragma unroll
        for (int nt = 0; nt < 16; ++nt) {
            bf16x8 b = *(const bf16x8*)&w1pad[(nt * 16 + rr) * 32 + q * 8];
            f32x4 z = {0.f, 0.f, 0.f, 0.f};
            hacc[nt] = __builtin_amdgcn_mfma_f32_16x16x32_bf16(a1, b, z, 0, 0, 0);
        }
        float meanj[4], rstdj[4];
        #pragma unroll
        for (int j = 0; j < 4; ++j) {
            float s = 0.f, z2 = 0.f;
            #pragma unroll
            for (int nt = 0; nt < 16; ++nt) { float v = hacc[nt][j]; s += v; z2 += v * v; }
            s  += __shfl_xor(s, 1);  s  += __shfl_xor(s, 2);
            s  += __shfl_xor(s, 4);  s  += __shfl_xor(s, 8);
            z2 += __shfl_xor(z2, 1); z2 += __shfl_xor(z2, 2);
            z2 += __shfl_xor(z2, 4); z2 += __shfl_xor(z2, 8);
            float mean = s * (1.f / 256.f);
            float var = fmaxf(z2 * (1.f / 256.f) - mean * mean, 0.f);
            meanj[j] = mean;
            rstdj[j] = 1.0f / sqrtf(var + 1e-5f);
        }
        #pragma unroll
        for (int nt = 0; nt < 16; ++nt) {
            const int c = nt * 16 + rr;
            const float gg = g1[c], bb = b1[c];
            #pragma unroll
            for (int j = 0; j < 4; ++j) {
                float v = (hacc[nt][j] - meanj[j]) * rstdj[j] * gg + bb;
                v = v > 0.f ? v : 0.1f * v;
                sw[(4 * q + j) * 264 + c] = f2bf(v);
            }
        }
        #pragma unroll
        for (int kb = 0; kb < 8; ++kb)
            afr[rt][kb] = *(const bf16x8*)&sw[rr * 264 + kb * 32 + q * 8];
    }
    __syncthreads();   // B half 0 + idxs ready

    const float* xp[2][4];
    #pragma unroll
    for (int rt = 0; rt < 2; ++rt)
        #pragma unroll
        for (int j = 0; j < 4; ++j)
            xp[rt][j] = xcur + (size_t)idxs[2 * w + rt][4 * q + j] * 256;

    float* prow[2] = { pooled + (size_t)(i0 + 2 * w) * 256,
                       pooled + (size_t)(i0 + 2 * w + 1) * 256 };

    // ---- half 0: output cols 0..127 (cols 0..63 go through conv) ----
    #pragma unroll 2
    for (int nt8 = 0; nt8 < 8; ++nt8) {
        const int c = nt8 * 16 + rr;
        #pragma unroll
        for (int rt = 0; rt < 2; ++rt) {
            f32x4 acc = {0.f, 0.f, 0.f, 0.f};
            #pragma unroll
            for (int kb = 0; kb < 8; ++kb) {
                bf16x8 b = *(const bf16x8*)&Bs[(nt8 * 16 + rr) * 264 + kb * 32 + q * 8];
                acc = __builtin_amdgcn_mfma_f32_16x16x32_bf16(afr[rt][kb], b, acc, 0, 0, 0);
            }
            float gv0 = xp[rt][0][c] + acc[0];
            float gv1 = xp[rt][1][c] + acc[1];
            float gv2 = xp[rt][2][c] + acc[2];
            float gv3 = xp[rt][3][c] + acc[3];
            if (nt8 < 4) {
                sw[(rt * 16 + 4 * q + 0) * 72 + c] = f2bf(gv0);
                sw[(rt * 16 + 4 * q + 1) * 72 + c] = f2bf(gv1);
                sw[(rt * 16 + 4 * q + 2) * 72 + c] = f2bf(gv2);
                sw[(rt * 16 + 4 * q + 3) * 72 + c] = f2bf(gv3);
            } else {
                float m = fmaxf(fmaxf(gv0, gv1), fmaxf(gv2, gv3));
                m = fmaxf(m, __shfl_xor(m, 16));
                m = fmaxf(m, __shfl_xor(m, 32));
                if (lane < 16) prow[rt][nt8 * 16 + lane] = m;
            }
        }
    }
    // ---- conv on cols 0..63 + pool ----
    #pragma unroll
    for (int rt = 0; rt < 2; ++rt) {
        const u16* gb = sw + rt * 1152;
        bf16x8 a20 = *(const bf16x8*)&gb[rr * 72 + q * 8];
        bf16x8 a21 = *(const bf16x8*)&gb[rr * 72 + 32 + q * 8];
        #pragma unroll
        for (int cn = 0; cn < 4; ++cn) {
            f32x4 acc = {0.f, 0.f, 0.f, 0.f};
            bf16x8 b20 = *(const bf16x8*)&convbf[(cn * 16 + rr) * 64 + q * 8];
            bf16x8 b21 = *(const bf16x8*)&convbf[(cn * 16 + rr) * 64 + 32 + q * 8];
            acc = __builtin_amdgcn_mfma_f32_16x16x32_bf16(a20, b20, acc, 0, 0, 0);
            acc = __builtin_amdgcn_mfma_f32_16x16x32_bf16(a21, b21, acc, 0, 0, 0);
            float m = fmaxf(fmaxf(acc[0], acc[1]), fmaxf(acc[2], acc[3]));
            m = fmaxf(m, __shfl_xor(m, 16));
            m = fmaxf(m, __shfl_xor(m, 32));
            if (lane < 16) prow[rt][cn * 16 + lane] = m;
        }
    }
    __syncthreads();   // done reading B half 0
    for (int o = tid * 16; o < 67584; o += 8192)
        *(uint4*)((char*)Bs + o) = *(const uint4*)((const char*)(ew2tp + 128 * 264) + o);
    __syncthreads();   // B half 1 ready

    // ---- half 1: output cols 128..255 (plain pool) ----
    #pragma unroll 2
    for (int nt8 = 0; nt8 < 8; ++nt8) {
        const int c = 128 + nt8 * 16 + rr;
        #pragma unroll
        for (int rt = 0; rt < 2; ++rt) {
            f32x4 acc = {0.f, 0.f, 0.f, 0.f};
            #pragma unroll
            for (int kb = 0; kb < 8; ++kb) {
                bf16x8 b = *(const bf16x8*)&Bs[(nt8 * 16 + rr) * 264 + kb * 32 + q * 8];
                acc = __builtin_amdgcn_mfma_f32_16x16x32_bf16(afr[rt][kb], b, acc, 0, 0, 0);
            }
            float gv0 = xp[rt][0][c] + acc[0];
            float gv1 = xp[rt][1][c] + acc[1];
            float gv2 = xp[rt][2][c] + acc[2];
            float gv3 = xp[rt][3][c] + acc[3];
            float m = fmaxf(fmaxf(gv0, gv1), fmaxf(gv2, gv3));
            m = fmaxf(m, __shfl_xor(m, 16));
            m = fmaxf(m, __shfl_xor(m, 32));
            if (lane < 16) prow[rt][128 + nt8 * 16 + lane] = m;
        }
    }
}

// ---------- pointwise stage v2: 64 rows/block, 512 threads; wave = (rowtile, col-half)
__global__ __launch_bounds__(512, 2) void k_pointwise(
    const float* pool,                 // [NPAD][256] fp32
    const float* __restrict__ xres,
    float*       xnext,                // may alias pool
    const u16*   __restrict__ b1t,     // pw_w1^T bf16 [1024][256]
    const float* __restrict__ g1, const float* __restrict__ b1,
    const u16*   __restrict__ b2t,     // pw_w2^T bf16 [256][1024]
    const float* __restrict__ g2, const float* __restrict__ b2,
    int guardRes)
{
    __shared__ u16 hm[64 * 1032];      // 132,096 B
    __shared__ float pst[64][2][2];    // per-row per-half {sum, sumsq}

    const int tid = threadIdx.x, w = tid >> 6, lane = tid & 63;
    const int rr = lane & 15, q = lane >> 4;
    const int rw = w & 3, ch = w >> 2;
    const size_t R0 = (size_t)blockIdx.x * 64 + (size_t)rw * 16;

    int arn = (int)R0 + rr; if (arn >= N_PTS) arn = N_PTS - 1;
    const float* arow = pool + (size_t)arn * 256;
    bf16x8 afr[8];
    #pragma unroll
    for (int kb = 0; kb < 8; ++kb) {
        float4 f0 = *(const float4*)(arow + kb * 32 + q * 8);
        float4 f1 = *(const float4*)(arow + kb * 32 + q * 8 + 4);
        bf16x8 a;
        a[0] = (short)f2bf(f0.x); a[1] = (short)f2bf(f0.y);
        a[2] = (short)f2bf(f0.z); a[3] = (short)f2bf(f0.w);
        a[4] = (short)f2bf(f1.x); a[5] = (short)f2bf(f1.y);
        a[6] = (short)f2bf(f1.z); a[7] = (short)f2bf(f1.w);
        afr[kb] = a;
    }
    // ---- GEMM1: this wave's 16 rows x its 512-col half ----
    float sums[4] = {0.f,0.f,0.f,0.f}, ssqs[4] = {0.f,0.f,0.f,0.f};
    #pragma unroll 2
    for (int ct = 0; ct < 32; ++ct) {
        const int co = ch * 512 + ct * 16 + rr;
        const u16* bp = b1t + (size_t)co * 256 + q * 8;
        f32x4 acc = {0.f, 0.f, 0.f, 0.f};
        #pragma unroll
        for (int kb = 0; kb < 8; ++kb) {
            bf16x8 b = *(const bf16x8*)(bp + kb * 32);
            acc = __builtin_amdgcn_mfma_f32_16x16x32_bf16(afr[kb], b, acc, 0, 0, 0);
        }
        #pragma unroll
        for (int j = 0; j < 4; ++j) {
            hm[(rw * 16 + 4 * q + j) * 1032 + co] = f2bf(acc[j]);
            sums[j] += acc[j]; ssqs[j] += acc[j] * acc[j];
        }
    }
    #pragma unroll
    for (int j = 0; j < 4; ++j) {
        float s = sums[j], z = ssqs[j];
        s += __shfl_xor(s, 1); s += __shfl_xor(s, 2);
        s += __shfl_xor(s, 4); s += __shfl_xor(s, 8);
        z += __shfl_xor(z, 1); z += __shfl_xor(z, 2);
        z += __shfl_xor(z, 4); z += __shfl_xor(z, 8);
        if (rr == 0) {
            pst[rw * 16 + 4 * q + j][ch][0] = s;
            pst[rw * 16 + 4 * q + j][ch][1] = z;
        }
    }
    __syncthreads();
    // ---- LN1 normalize + leaky (thread covers 128 cols of one row) ----
    {
        const int row = tid >> 3, cb = (tid & 7) * 128;
        float mean = (pst[row][0][0] + pst[row][1][0]) * (1.f / 1024.f);
        float vz = (pst[row][0][1] + pst[row][1][1]) * (1.f / 1024.f) - mean * mean;
        float rstd = 1.0f / sqrtf(fmaxf(vz, 0.f) + 1e-5f);
        u16* hp = hm + row * 1032 + cb;
        #pragma unroll 4
        for (int e = 0; e < 64; ++e) {
            uint32_t pk = *(uint32_t*)(hp + e * 2);
            float2 gg = *(const float2*)&g1[cb + 2 * e];
            float2 bb = *(const float2*)&b1[cb + 2 * e];
            float v0 = (bf2f((u16)(pk & 0xffffu)) - mean) * rstd * gg.x + bb.x;
            float v1 = (bf2f((u16)(pk >> 16)) - mean) * rstd * gg.y + bb.y;
            v0 = v0 > 0.f ? v0 : 0.1f * v0;
            v1 = v1 > 0.f ? v1 : 0.1f * v1;
            *(uint32_t*)(hp + e * 2) = (uint32_t)f2bf(v0) | ((uint32_t)f2bf(v1) << 16);
        }
    }
    __syncthreads();
    // ---- GEMM2: wave's 16 rows x its 128-col half, K=1024 ----
    const u16* ap = hm + (rw * 16 + rr) * 1032 + q * 8;
    bf16x8 a2[32];
    #pragma unroll
    for (int kb = 0; kb < 32; ++kb) a2[kb] = *(const bf16x8*)(ap + kb * 32);
    f32x4 acc2[8];
    #pragma unroll
    for (int ct = 0; ct < 8; ++ct) {
        const int cB = ch * 128 + ct * 16 + rr;
        const u16* bp = b2t + (size_t)cB * 1024 + q * 8;
        f32x4 aL = {0.f,0.f,0.f,0.f}, aH = {0.f,0.f,0.f,0.f};
        #pragma unroll
        for (int kb = 0; kb < 16; ++kb) {
            bf16x8 bL = *(const bf16x8*)(bp + kb * 32);
            bf16x8 bH = *(const bf16x8*)(bp + (kb + 16) * 32);
            aL = __builtin_amdgcn_mfma_f32_16x16x32_bf16(a2[kb], bL, aL, 0, 0, 0);
            aH = __builtin_amdgcn_mfma_f32_16x16x32_bf16(a2[kb + 16], bH, aH, 0, 0, 0);
        }
        acc2[ct] = aL + aH;
    }
    // ---- LN2 partials ----
    #pragma unroll
    for (int j = 0; j < 4; ++j) {
        float s = 0.f, z = 0.f;
        #pragma unroll
        for (int ct = 0; ct < 8; ++ct) { float v = acc2[ct][j]; s += v; z += v * v; }
        s += __shfl_xor(s, 1); s += __shfl_xor(s, 2);
        s += __shfl_xor(s, 4); s += __shfl_xor(s, 8);
        z += __shfl_xor(z, 1); z += __shfl_xor(z, 2);
        z += __shfl_xor(z, 4); z += __shfl_xor(z, 8);
        if (rr == 0) {
            pst[rw * 16 + 4 * q + j][ch][0] = s;
            pst[rw * 16 + 4 * q + j][ch][1] = z;
        }
    }
    __syncthreads();
    float mean2[4], rstd2[4];
    #pragma unroll
    for (int j = 0; j < 4; ++j) {
        const int row = rw * 16 + 4 * q + j;
        float s = pst[row][0][0] + pst[row][1][0];
        float z = pst[row][0][1] + pst[row][1][1];
        float mean = s * (1.f / 256.f);
        float var = fmaxf(z * (1.f / 256.f) - mean * mean, 0.f);
        mean2[j] = mean;
        rstd2[j] = 1.0f / sqrtf(var + 1e-5f);
    }
    // ---- epilogue: LN2 affine + residual + relu ----
    #pragma unroll
    for (int ct = 0; ct < 8; ++ct) {
        const int c = ch * 128 + ct * 16 + rr;
        const float gg = g2[c], bb = b2[c];
        #pragma unroll
        for (int j = 0; j < 4; ++j) {
            const size_t row = R0 + 4 * q + j;
            float v = (acc2[ct][j] - mean2[j]) * rstd2[j] * gg + bb;
            float xv = 0.f;
            if (!guardRes || row < (size_t)N_PTS) xv = xres[row * 256 + c];
            float o = v + xv;
            xnext[row * 256 + c] = o > 0.f ? o : 0.f;
        }
    }
}

// ---------- final projection: 128 rows/block, B staged in LDS halves
__global__ __launch_bounds__(512) void k_proj(
    const float* __restrict__ xin,   // [NPAD][256]
    const u16*   __restrict__ pjtp,  // proj_w^T padded bf16 [256][264]
    const float* __restrict__ pb,
    float*       __restrict__ out)   // [N][256]
{
    __shared__ u16 Bs[128 * 264];
    const int tid = threadIdx.x, w = tid >> 6, lane = tid & 63;
    const int rr = lane & 15, q = lane >> 4;
    const size_t R0 = (size_t)blockIdx.x * 128 + (size_t)w * 16;

    int arn = (int)R0 + rr; if (arn >= N_PTS) arn = N_PTS - 1;
    const float* arow = xin + (size_t)arn * 256;
    bf16x8 afr[8];
    #pragma unroll
    for (int kb = 0; kb < 8; ++kb) {
        float4 f0 = *(const float4*)(arow + kb * 32 + q * 8);
        float4 f1 = *(const float4*)(arow + kb * 32 + q * 8 + 4);
        bf16x8 a;
        a[0] = (short)f2bf(f0.x); a[1] = (short)f2bf(f0.y);
        a[2] = (short)f2bf(f0.z); a[3] = (short)f2bf(f0.w);
        a[4] = (short)f2bf(f1.x); a[5] = (short)f2bf(f1.y);
        a[6] = (short)f2bf(f1.z); a[7] = (short)f2bf(f1.w);
        afr[kb] = a;
    }
    #pragma unroll 1
    for (int h = 0; h < 2; ++h) {
        if (h) __syncthreads();
        for (int o = tid * 16; o < 67584; o += 8192)
            *(uint4*)((char*)Bs + o) = *(const uint4*)((const char*)(pjtp + h * 128 * 264) + o);
        __syncthreads();
        #pragma unroll 2
        for (int nt8 = 0; nt8 < 8; ++nt8) {
            f32x4 acc = {0.f, 0.f, 0.f, 0.f};
            #pragma unroll
            for (int kb = 0; kb < 8; ++kb) {
                bf16x8 b = *(const bf16x8*)&Bs[(nt8 * 16 + rr) * 264 + kb * 32 + q * 8];
                acc = __builtin_amdgcn_mfma_f32_16x16x32_bf16(afr[kb], b, acc, 0, 0, 0);
            }
            const int c = h * 128 + nt8 * 16 + rr;
            const float bias = pb[c];
            #pragma unroll
            for (int j = 0; j < 4; ++j) {
                const size_t row = R0 + 4 * q + j;
                if (row < (size_t)N_PTS) out[row * 256 + c] = acc[j] + bias;
            }
        }
    }
}

extern "C" void kernel_launch(void* const* d_in, const int* in_sizes, int n_in,
                              void* d_out, int out_size, void* d_ws, size_t ws_size,
                              hipStream_t stream) {
    const float* p      = (const float*)d_in[0];
    const float* x      = (const float*)d_in[1];
    const float* nn     = (const float*)d_in[2];
    const int*   idx    = (const int*)d_in[3];
    const float* r      = (const float*)d_in[4];
    const float* emb_w1 = (const float*)d_in[5];
    const float* emb_g1 = (const float*)d_in[6];
    const float* emb_b1 = (const float*)d_in[7];
    const float* emb_w2 = (const float*)d_in[8];
    const float* conv_w = (const float*)d_in[9];
    const float* pw_w1  = (const float*)d_in[10];
    const float* pw_g1  = (const float*)d_in[11];
    const float* pw_b1  = (const float*)d_in[12];
    const float* pw_w2  = (const float*)d_in[13];
    const float* pw_g2  = (const float*)d_in[14];
    const float* pw_b2  = (const float*)d_in[15];
    const float* proj_w = (const float*)d_in[16];
    const float* proj_b = (const float*)d_in[17];
    float* out = (float*)d_out;

    char* ws = (char*)d_ws;
    const size_t SZX = (size_t)NPAD * 256 * 4;
    float* P  = (float*)ws;
    float* X  = (float*)(ws + SZX);
    float* f5 = (float*)(ws + 2 * SZX);
    char*  wb = ws + 2 * SZX + (size_t)N_PTS * 16 * 5 * 4;
    u16* ew2tp  = (u16*)wb;                       // [2][256][264]
    u16* pjtp   = ew2tp + 2 * 256 * 264;          // [256][264]
    u16* w1pad  = pjtp + 256 * 264;               // [2][256][32]
    u16* convbf = w1pad + 2 * 256 * 32;           // [2][64][64]
    u16* b1t    = convbf + 2 * 64 * 64;           // [2][1024][256]
    u16* b2t    = b1t + 2 * 1024 * 256;           // [2][256][1024]

    // weight prep
    k_transpose_pad<<<(2*256*264 + 255)/256, 256, 0, stream>>>(emb_w2, ew2tp, 2, 256, 256, 264);
    k_transpose_pad<<<(256*264 + 255)/256, 256, 0, stream>>>(proj_w, pjtp, 1, 256, 256, 264);
    k_transpose_pad<<<(2*256*32 + 255)/256, 256, 0, stream>>>(emb_w1, w1pad, 2, 5, 256, 32);
    k_transpose_pad<<<(2*1024*256 + 255)/256, 256, 0, stream>>>(pw_w1, b1t, 2, 256, 1024, 256);
    k_transpose_pad<<<(2*256*1024 + 255)/256, 256, 0, stream>>>(pw_w2, b2t, 2, 1024, 256, 1024);
    k_cast_bf16<<<(2*64*64 + 255)/256, 256, 0, stream>>>(conv_w, convbf, 2*64*64);

    k_ppf<<<(N_PTS * 16 + 255)/256, 256, 0, stream>>>(p, nn, idx, r, f5);

    // layer 0
    k_neighbor<<<N_PTS/16, 512, 0, stream>>>(x, f5, idx, w1pad, emb_g1, emb_b1,
                                             ew2tp, convbf, P);
    k_pointwise<<<NPAD/64, 512, 0, stream>>>(P, x, P, b1t, pw_g1, pw_b1,
                                             b2t, pw_g2, pw_b2, 1);
    // layer 1
    k_neighbor<<<N_PTS/16, 512, 0, stream>>>(P, f5, idx, w1pad + 256*32,
                                             emb_g1 + 256, emb_b1 + 256,
                                             ew2tp + 256*264, convbf + 64*64, X);
    k_pointwise<<<NPAD/64, 512, 0, stream>>>(X, P, X, b1t + 1024*256,
                                             pw_g1 + 1024, pw_b1 + 1024,
                                             b2t + 256*1024, pw_g2 + 256, pw_b2 + 256, 0);
    // projection
    k_proj<<<(NPAD + 127)/128, 512, 0, stream>>>(X, pjtp, proj_b, out);
}

// Round 3
// 2770.938 us; speedup vs baseline: 1.6551x; 1.3678x over previous
//
#include <hip/hip_runtime.h>
#include <stdint.h>

#define N_PTS 100000
#define NPAD  100032   // 32*3126, 64-divisible

typedef unsigned short u16;
typedef unsigned int   u32;
using bf16x8 = __attribute__((ext_vector_type(8))) short;
using f32x4  = __attribute__((ext_vector_type(4))) float;

__device__ __forceinline__ u16 f2bf(float f) {
    u32 u = __float_as_uint(f);
    u += 0x7FFFu + ((u >> 16) & 1u);   // RNE
    return (u16)(u >> 16);
}
__device__ __forceinline__ float bf2f(u16 h) {
    return __uint_as_float(((u32)h) << 16);
}

// ---------- padded transpose to bf16: dst[l][co][stride] = src[l][ci][co] (ci<R else 0)
__global__ __launch_bounds__(256) void k_transpose_pad(
    const float* __restrict__ src, u16* __restrict__ dst,
    int Lc, int R, int Cc, int stride) {
    int t = blockIdx.x * 256 + threadIdx.x;
    int total = Lc * Cc * stride;
    if (t >= total) return;
    int l = t / (Cc * stride);
    int rem = t - l * (Cc * stride);
    int co = rem / stride;
    int ci = rem - co * stride;
    dst[t] = (ci < R) ? f2bf(src[((size_t)l * R + ci) * Cc + co]) : (u16)0;
}

__global__ __launch_bounds__(256) void k_cast_bf16(
    const float* __restrict__ src, u16* __restrict__ dst, int total) {
    int t = blockIdx.x * 256 + threadIdx.x;
    if (t < total) dst[t] = f2bf(src[t]);
}

// ---------- PPF features
__device__ __forceinline__ float angf(float ax, float ay, float az,
                                      float bx, float by, float bz) {
    float cx = ay * bz - az * by;
    float cy = az * bx - ax * bz;
    float cz = ax * by - ay * bx;
    float cr = sqrtf(cx * cx + cy * cy + cz * cz);
    float dt = ax * bx + ay * by + az * bz;
    return atan2f(cr, dt);
}

__global__ __launch_bounds__(256) void k_ppf(
    const float* __restrict__ p, const float* __restrict__ nrm,
    const int* __restrict__ idx, const float* __restrict__ r,
    float* __restrict__ f5) {
    int t = blockIdx.x * 256 + threadIdx.x;
    if (t >= N_PTS * 16) return;
    int i = t >> 4, k = t & 15;
    int j = idx[(size_t)i * 32 + k];
    float pix = p[(size_t)i*3], piy = p[(size_t)i*3+1], piz = p[(size_t)i*3+2];
    float pjx = p[(size_t)j*3], pjy = p[(size_t)j*3+1], pjz = p[(size_t)j*3+2];
    float dx = pjx - pix, dy = pjy - piy, dz = pjz - piz;
    float dist = sqrtf(dx*dx + dy*dy + dz*dz);
    float nix = nrm[(size_t)i*3], niy = nrm[(size_t)i*3+1], niz = nrm[(size_t)i*3+2];
    float njx = nrm[(size_t)j*3], njy = nrm[(size_t)j*3+1], njz = nrm[(size_t)j*3+2];
    float a1 = angf(nix, niy, niz, dx, dy, dz);
    float a2 = angf(njx, njy, njz, dx, dy, dz);
    float a3 = angf(nix, niy, niz, njx, njy, njz);
    float rinv = 1.0f / r[0];
    float* o = f5 + (size_t)t * 5;
    o[0] = a1; o[1] = a2; o[2] = a3; o[3] = dist; o[4] = dist * rinv;
}

// ---------- neighbor stage v3: 16 pts/block, 512 thr (8 waves), wave = 2 pts.
// GEMM writes pos to LDS; post-pass does coalesced float4 gathers + add + maxpool.
__global__ __launch_bounds__(512, 2) void k_neighbor(
    const float* __restrict__ xcur,
    const float* __restrict__ f5,
    const int*   __restrict__ idx,
    const u16*   __restrict__ w1pad,  // [256][32]
    const float* __restrict__ g1, const float* __restrict__ b1,
    const u16*   __restrict__ ew2tp,  // [256][264]
    const u16*   __restrict__ convbf, // [64][64]
    float*       __restrict__ pooled)
{
    __shared__ u16 Bs[128 * 264];     // 67,584 B
    __shared__ u16 swh[8][4352];      // 69,632 B: per-wave; emb h-stage (16x264) then e/g (2x16x136)
    __shared__ int idxs[16][16];

    const int tid = threadIdx.x, w = tid >> 6, lane = tid & 63;
    const int rr = lane & 15, q = lane >> 4;
    const int i0 = blockIdx.x * 16;

    for (int o = tid * 16; o < 67584; o += 8192)
        *(uint4*)((char*)Bs + o) = *(const uint4*)((const char*)ew2tp + o);
    if (tid < 256)
        idxs[tid >> 4][tid & 15] = idx[(size_t)(i0 + (tid >> 4)) * 32 + (tid & 15)];

    u16* sw = &swh[w][0];
    bf16x8 afr[2][8];

    // ---- emb MLP per point: h = leaky(LN(f5pad @ w1)) -> A-frags in regs ----
    #pragma unroll
    for (int rt = 0; rt < 2; ++rt) {
        const int pt = i0 + 2 * w + rt;
        bf16x8 a1;
        #pragma unroll
        for (int e = 0; e < 8; ++e) a1[e] = 0;
        if (q == 0) {
            const float* fp = f5 + ((size_t)pt * 16 + rr) * 5;
            a1[0] = (short)f2bf(fp[0]); a1[1] = (short)f2bf(fp[1]);
            a1[2] = (short)f2bf(fp[2]); a1[3] = (short)f2bf(fp[3]);
            a1[4] = (short)f2bf(fp[4]);
        }
        f32x4 hacc[16];
        #pragma unroll
        for (int nt = 0; nt < 16; ++nt) {
            bf16x8 b = *(const bf16x8*)&w1pad[(nt * 16 + rr) * 32 + q * 8];
            f32x4 z = {0.f, 0.f, 0.f, 0.f};
            hacc[nt] = __builtin_amdgcn_mfma_f32_16x16x32_bf16(a1, b, z, 0, 0, 0);
        }
        float meanj[4], rstdj[4];
        #pragma unroll
        for (int j = 0; j < 4; ++j) {
            float s = 0.f, z2 = 0.f;
            #pragma unroll
            for (int nt = 0; nt < 16; ++nt) { float v = hacc[nt][j]; s += v; z2 += v * v; }
            s  += __shfl_xor(s, 1);  s  += __shfl_xor(s, 2);
            s  += __shfl_xor(s, 4);  s  += __shfl_xor(s, 8);
            z2 += __shfl_xor(z2, 1); z2 += __shfl_xor(z2, 2);
            z2 += __shfl_xor(z2, 4); z2 += __shfl_xor(z2, 8);
            float mean = s * (1.f / 256.f);
            float var = fmaxf(z2 * (1.f / 256.f) - mean * mean, 0.f);
            meanj[j] = mean;
            rstdj[j] = 1.0f / sqrtf(var + 1e-5f);
        }
        #pragma unroll
        for (int nt = 0; nt < 16; ++nt) {
            const int c = nt * 16 + rr;
            const float gg = g1[c], bb = b1[c];
            #pragma unroll
            for (int j = 0; j < 4; ++j) {
                float v = (hacc[nt][j] - meanj[j]) * rstdj[j] * gg + bb;
                v = v > 0.f ? v : 0.1f * v;
                sw[(4 * q + j) * 264 + c] = f2bf(v);
            }
        }
        #pragma unroll
        for (int kb = 0; kb < 8; ++kb)
            afr[rt][kb] = *(const bf16x8*)&sw[rr * 264 + kb * 32 + q * 8];
    }
    __syncthreads();   // (1) Bs half0 + idxs ready; h-stage consumed

    const int ppt = lane >> 5;            // post-pass: point 0/1
    const int cq  = (lane & 31) * 4;      // post-pass: col quad within half

    // ================= half 0: cols 0..127 =================
    #pragma unroll 2
    for (int nt8 = 0; nt8 < 8; ++nt8) {
        bf16x8 bb[8];
        #pragma unroll
        for (int kb = 0; kb < 8; ++kb)
            bb[kb] = *(const bf16x8*)&Bs[(nt8 * 16 + rr) * 264 + kb * 32 + q * 8];
        f32x4 a0 = {0.f,0.f,0.f,0.f}, a1v = {0.f,0.f,0.f,0.f};
        #pragma unroll
        for (int kb = 0; kb < 8; ++kb) {
            a0  = __builtin_amdgcn_mfma_f32_16x16x32_bf16(afr[0][kb], bb[kb], a0, 0, 0, 0);
            a1v = __builtin_amdgcn_mfma_f32_16x16x32_bf16(afr[1][kb], bb[kb], a1v, 0, 0, 0);
        }
        const int ch = nt8 * 16 + rr;
        #pragma unroll
        for (int j = 0; j < 4; ++j) {
            sw[(4 * q + j) * 136 + ch]        = f2bf(a0[j]);
            sw[(16 + 4 * q + j) * 136 + ch]   = f2bf(a1v[j]);
        }
    }
    __syncthreads();   // (2) all waves done with Bs half0

    // issue half-1 staging first (overlaps with gathers below)
    for (int o = tid * 16; o < 67584; o += 8192)
        *(uint4*)((char*)Bs + o) = *(const uint4*)((const char*)(ew2tp + 128 * 264) + o);

    // ---- post-pass half 0: coalesced gathers; g for c<64 back to LDS; pool c in [64,128) ----
    {
        const int* ix = idxs[2 * w + ppt];
        float4 xg[16];
        #pragma unroll
        for (int k = 0; k < 16; ++k)
            xg[k] = *(const float4*)(xcur + (size_t)ix[k] * 256 + cq);
        float4 m4 = {-1e30f, -1e30f, -1e30f, -1e30f};
        #pragma unroll
        for (int k = 0; k < 16; ++k) {
            uint2 pk = *(const uint2*)&sw[(ppt * 16 + k) * 136 + cq];
            float g0 = bf2f((u16)(pk.x & 0xffffu)) + xg[k].x;
            float g1v = bf2f((u16)(pk.x >> 16))    + xg[k].y;
            float g2 = bf2f((u16)(pk.y & 0xffffu)) + xg[k].z;
            float g3 = bf2f((u16)(pk.y >> 16))     + xg[k].w;
            if (cq < 64) {
                uint2 o2;
                o2.x = (u32)f2bf(g0) | ((u32)f2bf(g1v) << 16);
                o2.y = (u32)f2bf(g2) | ((u32)f2bf(g3) << 16);
                *(uint2*)&sw[(ppt * 16 + k) * 136 + cq] = o2;
            } else {
                m4.x = fmaxf(m4.x, g0); m4.y = fmaxf(m4.y, g1v);
                m4.z = fmaxf(m4.z, g2); m4.w = fmaxf(m4.w, g3);
            }
        }
        if (cq >= 64)
            *(float4*)(pooled + (size_t)(i0 + 2 * w + ppt) * 256 + cq) = *(float4*)&m4;
    }
    // ---- conv on g[:, :64] per point + pool ----
    #pragma unroll
    for (int pt2 = 0; pt2 < 2; ++pt2) {
        const u16* gb = sw + pt2 * 16 * 136;
        bf16x8 a20 = *(const bf16x8*)&gb[rr * 136 + q * 8];
        bf16x8 a21 = *(const bf16x8*)&gb[rr * 136 + 32 + q * 8];
        #pragma unroll
        for (int cn = 0; cn < 4; ++cn) {
            f32x4 acc = {0.f, 0.f, 0.f, 0.f};
            bf16x8 b20 = *(const bf16x8*)&convbf[(cn * 16 + rr) * 64 + q * 8];
            bf16x8 b21 = *(const bf16x8*)&convbf[(cn * 16 + rr) * 64 + 32 + q * 8];
            acc = __builtin_amdgcn_mfma_f32_16x16x32_bf16(a20, b20, acc, 0, 0, 0);
            acc = __builtin_amdgcn_mfma_f32_16x16x32_bf16(a21, b21, acc, 0, 0, 0);
            float m = fmaxf(fmaxf(acc[0], acc[1]), fmaxf(acc[2], acc[3]));
            m = fmaxf(m, __shfl_xor(m, 16));
            m = fmaxf(m, __shfl_xor(m, 32));
            if (lane < 16)
                pooled[(size_t)(i0 + 2 * w + pt2) * 256 + cn * 16 + lane] = m;
        }
    }
    __syncthreads();   // (3) Bs half1 ready

    // ================= half 1: cols 128..255 =================
    #pragma unroll 2
    for (int nt8 = 0; nt8 < 8; ++nt8) {
        bf16x8 bb[8];
        #pragma unroll
        for (int kb = 0; kb < 8; ++kb)
            bb[kb] = *(const bf16x8*)&Bs[(nt8 * 16 + rr) * 264 + kb * 32 + q * 8];
        f32x4 a0 = {0.f,0.f,0.f,0.f}, a1v = {0.f,0.f,0.f,0.f};
        #pragma unroll
        for (int kb = 0; kb < 8; ++kb) {
            a0  = __builtin_amdgcn_mfma_f32_16x16x32_bf16(afr[0][kb], bb[kb], a0, 0, 0, 0);
            a1v = __builtin_amdgcn_mfma_f32_16x16x32_bf16(afr[1][kb], bb[kb], a1v, 0, 0, 0);
        }
        const int ch = nt8 * 16 + rr;
        #pragma unroll
        for (int j = 0; j < 4; ++j) {
            sw[(4 * q + j) * 136 + ch]      = f2bf(a0[j]);
            sw[(16 + 4 * q + j) * 136 + ch] = f2bf(a1v[j]);
        }
    }
    // per-wave buffer: only this wave's lanes read -> no block barrier needed
    {
        const int* ix = idxs[2 * w + ppt];
        float4 xg[16];
        #pragma unroll
        for (int k = 0; k < 16; ++k)
            xg[k] = *(const float4*)(xcur + (size_t)ix[k] * 256 + 128 + cq);
        float4 m4 = {-1e30f, -1e30f, -1e30f, -1e30f};
        #pragma unroll
        for (int k = 0; k < 16; ++k) {
            uint2 pk = *(const uint2*)&sw[(ppt * 16 + k) * 136 + cq];
            m4.x = fmaxf(m4.x, bf2f((u16)(pk.x & 0xffffu)) + xg[k].x);
            m4.y = fmaxf(m4.y, bf2f((u16)(pk.x >> 16))     + xg[k].y);
            m4.z = fmaxf(m4.z, bf2f((u16)(pk.y & 0xffffu)) + xg[k].z);
            m4.w = fmaxf(m4.w, bf2f((u16)(pk.y >> 16))     + xg[k].w);
        }
        *(float4*)(pooled + (size_t)(i0 + 2 * w + ppt) * 256 + 128 + cq) = *(float4*)&m4;
    }
}

// ---------- pointwise v4: 32 rows/block, 512 thr, 8 waves split by COLUMN only.
// hm = 66KB -> 2 blocks/CU -> 4 waves/SIMD. Register-light (<=128 VGPR).
__global__ __launch_bounds__(512, 4) void k_pointwise(
    const float* pool,
    const float* __restrict__ xres,
    float*       xnext,
    const u16*   __restrict__ b1t,     // [1024][256]
    const float* __restrict__ g1, const float* __restrict__ b1,
    const u16*   __restrict__ b2t,     // [256][1024]
    const float* __restrict__ g2, const float* __restrict__ b2,
    int guardRes)
{
    __shared__ u16 hm[32 * 1032];      // 66,048 B
    __shared__ float pst[32][8][2];

    const int tid = threadIdx.x, w = tid >> 6, lane = tid & 63;
    const int rr = lane & 15, q = lane >> 4;
    const size_t R0 = (size_t)blockIdx.x * 32;

    // A fragments for 2 row-tiles (rows R0..R0+31)
    bf16x8 afr[2][8];
    #pragma unroll
    for (int rt = 0; rt < 2; ++rt) {
        int ar = (int)R0 + rt * 16 + rr; if (ar >= N_PTS) ar = N_PTS - 1;
        const float* arow = pool + (size_t)ar * 256;
        #pragma unroll
        for (int kb = 0; kb < 8; ++kb) {
            float4 f0 = *(const float4*)(arow + kb * 32 + q * 8);
            float4 f1 = *(const float4*)(arow + kb * 32 + q * 8 + 4);
            bf16x8 a;
            a[0] = (short)f2bf(f0.x); a[1] = (short)f2bf(f0.y);
            a[2] = (short)f2bf(f0.z); a[3] = (short)f2bf(f0.w);
            a[4] = (short)f2bf(f1.x); a[5] = (short)f2bf(f1.y);
            a[6] = (short)f2bf(f1.z); a[7] = (short)f2bf(f1.w);
            afr[rt][kb] = a;
        }
    }

    // ---- GEMM1: wave covers cols [w*128, w*128+128), all 32 rows ----
    #pragma unroll 2
    for (int ct = 0; ct < 8; ++ct) {
        const int co = w * 128 + ct * 16 + rr;
        const u16* bp = b1t + (size_t)co * 256 + q * 8;
        bf16x8 bb[8];
        #pragma unroll
        for (int kb = 0; kb < 8; ++kb) bb[kb] = *(const bf16x8*)(bp + kb * 32);
        f32x4 a0 = {0.f,0.f,0.f,0.f}, a1v = {0.f,0.f,0.f,0.f};
        #pragma unroll
        for (int kb = 0; kb < 8; ++kb) {
            a0  = __builtin_amdgcn_mfma_f32_16x16x32_bf16(afr[0][kb], bb[kb], a0, 0, 0, 0);
            a1v = __builtin_amdgcn_mfma_f32_16x16x32_bf16(afr[1][kb], bb[kb], a1v, 0, 0, 0);
        }
        #pragma unroll
        for (int j = 0; j < 4; ++j) {
            hm[(4 * q + j) * 1032 + co]        = f2bf(a0[j]);
            hm[(16 + 4 * q + j) * 1032 + co]   = f2bf(a1v[j]);
        }
    }
    __syncthreads();

    // ---- LN1 (read-back stats, in-wave reduce) + normalize + leaky ----
    {
        const int row = tid >> 4;       // 0..31
        const int t16 = tid & 15;
        u32* hm32 = (u32*)hm;
        const int base = row * 516;
        float s = 0.f, z = 0.f;
        #pragma unroll 8
        for (int e = 0; e < 32; ++e) {
            u32 pk = hm32[base + t16 + 16 * e];
            float v0 = bf2f((u16)(pk & 0xffffu)), v1 = bf2f((u16)(pk >> 16));
            s += v0 + v1; z += v0 * v0 + v1 * v1;
        }
        s += __shfl_xor(s, 1); s += __shfl_xor(s, 2);
        s += __shfl_xor(s, 4); s += __shfl_xor(s, 8);
        z += __shfl_xor(z, 1); z += __shfl_xor(z, 2);
        z += __shfl_xor(z, 4); z += __shfl_xor(z, 8);
        float mean = s * (1.f / 1024.f);
        float var = fmaxf(z * (1.f / 1024.f) - mean * mean, 0.f);
        float rstd = 1.0f / sqrtf(var + 1e-5f);
        #pragma unroll 4
        for (int e = 0; e < 32; ++e) {
            const int cidx = t16 + 16 * e;
            u32 pk = hm32[base + cidx];
            const int c = cidx * 2;
            float2 gg = *(const float2*)&g1[c];
            float2 bbv = *(const float2*)&b1[c];
            float v0 = (bf2f((u16)(pk & 0xffffu)) - mean) * rstd * gg.x + bbv.x;
            float v1 = (bf2f((u16)(pk >> 16))     - mean) * rstd * gg.y + bbv.y;
            v0 = v0 > 0.f ? v0 : 0.1f * v0;
            v1 = v1 > 0.f ? v1 : 0.1f * v1;
            hm32[base + cidx] = (u32)f2bf(v0) | ((u32)f2bf(v1) << 16);
        }
    }
    __syncthreads();

    // ---- GEMM2: wave covers out cols [w*32, w*32+32), K=1024, 2 row chains ----
    f32x4 acc2[2][2];
    #pragma unroll
    for (int ct = 0; ct < 2; ++ct) {
        const int cB = w * 32 + ct * 16 + rr;
        const u16* bp = b2t + (size_t)cB * 1024 + q * 8;
        f32x4 c0 = {0.f,0.f,0.f,0.f}, c1 = {0.f,0.f,0.f,0.f};
        #pragma unroll 8
        for (int kb = 0; kb < 32; ++kb) {
            bf16x8 b  = *(const bf16x8*)(bp + kb * 32);
            bf16x8 a0 = *(const bf16x8*)&hm[rr * 1032 + kb * 32 + q * 8];
            bf16x8 a1 = *(const bf16x8*)&hm[(16 + rr) * 1032 + kb * 32 + q * 8];
            c0 = __builtin_amdgcn_mfma_f32_16x16x32_bf16(a0, b, c0, 0, 0, 0);
            c1 = __builtin_amdgcn_mfma_f32_16x16x32_bf16(a1, b, c1, 0, 0, 0);
        }
        acc2[0][ct] = c0; acc2[1][ct] = c1;
    }

    // ---- LN2 partial stats -> pst ----
    #pragma unroll
    for (int rt = 0; rt < 2; ++rt) {
        #pragma unroll
        for (int j = 0; j < 4; ++j) {
            float s = acc2[rt][0][j] + acc2[rt][1][j];
            float z = acc2[rt][0][j] * acc2[rt][0][j] + acc2[rt][1][j] * acc2[rt][1][j];
            s += __shfl_xor(s, 1); s += __shfl_xor(s, 2);
            s += __shfl_xor(s, 4); s += __shfl_xor(s, 8);
            z += __shfl_xor(z, 1); z += __shfl_xor(z, 2);
            z += __shfl_xor(z, 4); z += __shfl_xor(z, 8);
            if (rr == 0) {
                pst[rt * 16 + 4 * q + j][w][0] = s;
                pst[rt * 16 + 4 * q + j][w][1] = z;
            }
        }
    }
    __syncthreads();

    // ---- LN2 finalize + residual + relu ----
    #pragma unroll
    for (int rt = 0; rt < 2; ++rt) {
        float mean2[4], rstd2[4];
        #pragma unroll
        for (int j = 0; j < 4; ++j) {
            const int row = rt * 16 + 4 * q + j;
            float s = 0.f, z = 0.f;
            #pragma unroll
            for (int k = 0; k < 8; ++k) { s += pst[row][k][0]; z += pst[row][k][1]; }
            float mean = s * (1.f / 256.f);
            float var = fmaxf(z * (1.f / 256.f) - mean * mean, 0.f);
            mean2[j] = mean;
            rstd2[j] = 1.0f / sqrtf(var + 1e-5f);
        }
        #pragma unroll
        for (int ct = 0; ct < 2; ++ct) {
            const int c = w * 32 + ct * 16 + rr;
            const float gg = g2[c], bb = b2[c];
            #pragma unroll
            for (int j = 0; j < 4; ++j) {
                const size_t row = R0 + rt * 16 + 4 * q + j;
                float v = (acc2[rt][ct][j] - mean2[j]) * rstd2[j] * gg + bb;
                float xv = 0.f;
                if (!guardRes || row < (size_t)N_PTS) xv = xres[row * 256 + c];
                float o = v + xv;
                xnext[row * 256 + c] = o > 0.f ? o : 0.f;
            }
        }
    }
}

// ---------- final projection: 128 rows/block, B staged in LDS halves
__global__ __launch_bounds__(512, 4) void k_proj(
    const float* __restrict__ xin,
    const u16*   __restrict__ pjtp,  // [256][264]
    const float* __restrict__ pb,
    float*       __restrict__ out)
{
    __shared__ u16 Bs[128 * 264];
    const int tid = threadIdx.x, w = tid >> 6, lane = tid & 63;
    const int rr = lane & 15, q = lane >> 4;
    const size_t R0 = (size_t)blockIdx.x * 128 + (size_t)w * 16;

    int arn = (int)R0 + rr; if (arn >= N_PTS) arn = N_PTS - 1;
    const float* arow = xin + (size_t)arn * 256;
    bf16x8 afr[8];
    #pragma unroll
    for (int kb = 0; kb < 8; ++kb) {
        float4 f0 = *(const float4*)(arow + kb * 32 + q * 8);
        float4 f1 = *(const float4*)(arow + kb * 32 + q * 8 + 4);
        bf16x8 a;
        a[0] = (short)f2bf(f0.x); a[1] = (short)f2bf(f0.y);
        a[2] = (short)f2bf(f0.z); a[3] = (short)f2bf(f0.w);
        a[4] = (short)f2bf(f1.x); a[5] = (short)f2bf(f1.y);
        a[6] = (short)f2bf(f1.z); a[7] = (short)f2bf(f1.w);
        afr[kb] = a;
    }
    #pragma unroll 1
    for (int h = 0; h < 2; ++h) {
        if (h) __syncthreads();
        for (int o = tid * 16; o < 67584; o += 8192)
            *(uint4*)((char*)Bs + o) = *(const uint4*)((const char*)(pjtp + h * 128 * 264) + o);
        __syncthreads();
        #pragma unroll 2
        for (int nt8 = 0; nt8 < 8; ++nt8) {
            f32x4 acc = {0.f, 0.f, 0.f, 0.f};
            #pragma unroll
            for (int kb = 0; kb < 8; ++kb) {
                bf16x8 b = *(const bf16x8*)&Bs[(nt8 * 16 + rr) * 264 + kb * 32 + q * 8];
                acc = __builtin_amdgcn_mfma_f32_16x16x32_bf16(afr[kb], b, acc, 0, 0, 0);
            }
            const int c = h * 128 + nt8 * 16 + rr;
            const float bias = pb[c];
            #pragma unroll
            for (int j = 0; j < 4; ++j) {
                const size_t row = R0 + 4 * q + j;
                if (row < (size_t)N_PTS) out[row * 256 + c] = acc[j] + bias;
            }
        }
    }
}

extern "C" void kernel_launch(void* const* d_in, const int* in_sizes, int n_in,
                              void* d_out, int out_size, void* d_ws, size_t ws_size,
                              hipStream_t stream) {
    const float* p      = (const float*)d_in[0];
    const float* x      = (const float*)d_in[1];
    const float* nn     = (const float*)d_in[2];
    const int*   idx    = (const int*)d_in[3];
    const float* r      = (const float*)d_in[4];
    const float* emb_w1 = (const float*)d_in[5];
    const float* emb_g1 = (const float*)d_in[6];
    const float* emb_b1 = (const float*)d_in[7];
    const float* emb_w2 = (const float*)d_in[8];
    const float* conv_w = (const float*)d_in[9];
    const float* pw_w1  = (const float*)d_in[10];
    const float* pw_g1  = (const float*)d_in[11];
    const float* pw_b1  = (const float*)d_in[12];
    const float* pw_w2  = (const float*)d_in[13];
    const float* pw_g2  = (const float*)d_in[14];
    const float* pw_b2  = (const float*)d_in[15];
    const float* proj_w = (const float*)d_in[16];
    const float* proj_b = (const float*)d_in[17];
    float* out = (float*)d_out;

    char* ws = (char*)d_ws;
    const size_t SZX = (size_t)NPAD * 256 * 4;
    float* P  = (float*)ws;
    float* X  = (float*)(ws + SZX);
    float* f5 = (float*)(ws + 2 * SZX);
    char*  wb = ws + 2 * SZX + (size_t)N_PTS * 16 * 5 * 4;
    u16* ew2tp  = (u16*)wb;                       // [2][256][264]
    u16* pjtp   = ew2tp + 2 * 256 * 264;          // [256][264]
    u16* w1pad  = pjtp + 256 * 264;               // [2][256][32]
    u16* convbf = w1pad + 2 * 256 * 32;           // [2][64][64]
    u16* b1t    = convbf + 2 * 64 * 64;           // [2][1024][256]
    u16* b2t    = b1t + 2 * 1024 * 256;           // [2][256][1024]

    k_transpose_pad<<<(2*256*264 + 255)/256, 256, 0, stream>>>(emb_w2, ew2tp, 2, 256, 256, 264);
    k_transpose_pad<<<(256*264 + 255)/256, 256, 0, stream>>>(proj_w, pjtp, 1, 256, 256, 264);
    k_transpose_pad<<<(2*256*32 + 255)/256, 256, 0, stream>>>(emb_w1, w1pad, 2, 5, 256, 32);
    k_transpose_pad<<<(2*1024*256 + 255)/256, 256, 0, stream>>>(pw_w1, b1t, 2, 256, 1024, 256);
    k_transpose_pad<<<(2*256*1024 + 255)/256, 256, 0, stream>>>(pw_w2, b2t, 2, 1024, 256, 1024);
    k_cast_bf16<<<(2*64*64 + 255)/256, 256, 0, stream>>>(conv_w, convbf, 2*64*64);

    k_ppf<<<(N_PTS * 16 + 255)/256, 256, 0, stream>>>(p, nn, idx, r, f5);

    // layer 0
    k_neighbor<<<N_PTS/16, 512, 0, stream>>>(x, f5, idx, w1pad, emb_g1, emb_b1,
                                             ew2tp, convbf, P);
    k_pointwise<<<NPAD/32, 512, 0, stream>>>(P, x, P, b1t, pw_g1, pw_b1,
                                             b2t, pw_g2, pw_b2, 1);
    // layer 1
    k_neighbor<<<N_PTS/16, 512, 0, stream>>>(P, f5, idx, w1pad + 256*32,
                                             emb_g1 + 256, emb_b1 + 256,
                                             ew2tp + 256*264, convbf + 64*64, X);
    k_pointwise<<<NPAD/32, 512, 0, stream>>>(X, P, X, b1t + 1024*256,
                                             pw_g1 + 1024, pw_b1 + 1024,
                                             b2t + 256*1024, pw_g2 + 256, pw_b2 + 256, 0);
    // projection
    k_proj<<<(NPAD + 127)/128, 512, 0, stream>>>(X, pjtp, proj_b, out);
}